// Round 20
// baseline (381.563 us; speedup 1.0000x reference)
//
#include <hip/hip_runtime.h>
#include <cmath>

// SSIM loss, vertical-first row-sliding kernel, merged 3D+2D dispatch.
// Round-20 = round-14's champion kernel body byte-for-byte (2 output rows
// per barrier interval, 12-slot f32x2 ring, 4 LDS sets / 42 KB,
// launch_bounds(256,4) -> VGPR 68 no spill, grid 1792 = 1536 3D + 256 2D)
// with the serial 12-us depth-mean dispatch FUSED in as a producer-consumer
// prologue: every block computes a 147-float4 chunk of b2 = mean16(img2)
// at entry (+threadfence +device counter); only the 256 2D blocks (last in
// grid) spin on the counter before their first b2 read. Spinners (256) <
// block capacity (~768) and every block produces before spinning -> no
// deadlock. Counter zeroed by the per-launch memset -> graph-replay safe.

#define WSZ 11
#define IMG 512
#define SLICE (IMG * IMG)
#define NBLK 1792
#define MEAN_N (4 * SLICE / 4)          // 262144 float4 elements of b2
#define CHUNK ((MEAN_N + NBLK - 1) / NBLK)   // 147

typedef float f32x2 __attribute__((ext_vector_type(2)));
typedef float f32x4 __attribute__((ext_vector_type(4)));

struct G11 { float w[WSZ]; };

// LDS-visibility-only barrier: wait own LDS ops, rendezvous; vmem stays in flight.
__device__ __forceinline__ void row_barrier()
{
    asm volatile("s_waitcnt lgkmcnt(0)" ::: "memory");
    __builtin_amdgcn_s_barrier();
}

__global__ __launch_bounds__(256, 4)
void ssim_pk_kernel(const float* __restrict__ A3, const float* __restrict__ B3,
                    const float* __restrict__ A2, float4* __restrict__ b2,
                    double* __restrict__ acc, unsigned int* __restrict__ cnt,
                    G11 gw)
{
    __shared__ f32x4 A4[4][262];   // (m1,m2) pairs, 3-slot pad each side
    __shared__ f32x4 B4[4][262];   // (xx,yy) pairs
    __shared__ f32x2 Z2[4][262];   // zz pairs
    __shared__ float bsum[4];

    const int tx = threadIdx.x;    // 0..255 = column pair index
    const int x0 = tx * 2;
    const int unit = blockIdx.x;

    // ---- producer prologue: this block's chunk of b2 = mean16(img2) ----
    {
        int e = unit * CHUNK + tx;
        if (tx < CHUNK && e < MEAN_N) {
            const int per = SLICE / 4;
            int img = e >> 16;                 // / per (per = 65536)
            int p   = e & (per - 1);
            const float4* src = (const float4*)B3 + (long)img * 16 * per + p;
            float sx = 0.f, sy = 0.f, sz = 0.f, sw = 0.f;
            #pragma unroll
            for (int d = 0; d < 16; d++) {
                float4 v = src[(long)d * per];
                sx += v.x; sy += v.y; sz += v.z; sw += v.w;
            }
            float4 o;
            o.x = sx * 0.0625f; o.y = sy * 0.0625f;
            o.z = sz * 0.0625f; o.w = sw * 0.0625f;
            b2[e] = o;
        }
        __threadfence();                       // device-scope release of b2 chunk
        __syncthreads();
        if (tx == 0)
            __hip_atomic_fetch_add(cnt, 1u, __ATOMIC_RELEASE, __HIP_MEMORY_SCOPE_AGENT);
    }

    // decode work unit: [0,1536) = 3D slice-bands (24/slice: 16x22 + 8x20
    // rows), [1536,1792) = 2D bands LAST (4 imgs x 64 bands of 8 rows)
    const float* Ap;
    const float* Bp;
    double* accp;
    int y0, BAND;
    if (unit < 1536) {
        int slice = unit / 24;
        int band  = unit - slice * 24;
        Ap = A3 + (long)slice * SLICE;
        Bp = B3 + (long)slice * SLICE;
        accp = acc + 0;
        if (band < 16) { y0 = band * 22;              BAND = 22; }
        else           { y0 = 352 + (band - 16) * 20; BAND = 20; }
    } else {
        int uu = unit - 1536;
        int img  = uu >> 6;
        int band = uu & 63;
        Ap = A2 + (long)img * SLICE;
        Bp = (const float*)b2 + (long)img * SLICE;
        accp = acc + 1;
        y0 = band * 8;
        BAND = 8;

        // ---- consumer gate: wait until all 1792 chunks of b2 are written ----
        if (tx == 0) {
            while (__hip_atomic_load(cnt, __ATOMIC_ACQUIRE, __HIP_MEMORY_SCOPE_AGENT)
                   < (unsigned)NBLK) { __builtin_amdgcn_s_sleep(8); }
        }
        __syncthreads();
        __threadfence();                       // acquire: b2 visible
    }
    const int ITER = BAND >> 1;    // 2 output rows per iteration

    // zero pads: pair slots 0..2 and 259..261, all 4 buffer sets
    if (tx < 3) {
        f32x4 z4 = {0.f, 0.f, 0.f, 0.f};
        f32x2 z2 = {0.f, 0.f};
        #pragma unroll
        for (int b = 0; b < 4; b++) {
            A4[b][tx] = z4; A4[b][259 + tx] = z4;
            B4[b][tx] = z4; B4[b][259 + tx] = z4;
            Z2[b][tx] = z2; Z2[b][259 + tx] = z2;
        }
    }

    // 12-slot register ring of raw (a,b) pairs; slot = t % 12, t = row - (y0-5)
    f32x2 ra[12], rb[12];

    float sum = 0.f;
    const f32x2 C1v = {1e-4f, 1e-4f};
    const f32x2 C2v = {9e-4f, 9e-4f};

    // warmup: insert input rows t = 0..9 (rows y0-5 .. y0+4)
    #pragma unroll
    for (int t = 0; t < 10; t++) {
        int r = y0 - 5 + t;
        f32x2 a = {0.f, 0.f}, b = {0.f, 0.f};
        if (r >= 0) {                       // r < IMG always in warmup
            a = *(const f32x2*)&Ap[(long)r * IMG + x0];
            b = *(const f32x2*)&Bp[(long)r * IMG + x0];
        }
        ra[t] = a; rb[t] = b;
    }
    ra[10] = (f32x2){0.f, 0.f}; rb[10] = (f32x2){0.f, 0.f};
    ra[11] = (f32x2){0.f, 0.f}; rb[11] = (f32x2){0.f, 0.f};

    // prefetch iteration 0's two input rows (t = 10, 11 -> rows y0+5, y0+6)
    f32x2 aN0 = {0.f, 0.f}, bN0 = aN0, aN1 = aN0, bN1 = aN0;
    {
        int r0 = y0 + 5, r1 = y0 + 6;
        if (r0 < IMG) { aN0 = *(const f32x2*)&Ap[(long)r0 * IMG + x0];
                        bN0 = *(const f32x2*)&Bp[(long)r0 * IMG + x0]; }
        if (r1 < IMG) { aN1 = *(const f32x2*)&Ap[(long)r1 * IMG + x0];
                        bN1 = *(const f32x2*)&Bp[(long)r1 * IMG + x0]; }
    }

    // vertical 11-tap for one output row; slots (base+j)%12, weights g[j]
    auto vpass = [&](int base, int buf) {
        f32x2 m1 = {0.f, 0.f}, m2 = m1, xx = m1, yy = m1, zz = m1;
        #pragma unroll
        for (int j = 0; j < 11; j++) {
            const int s = (base + j) % 12;           // compile-time
            const f32x2 g2 = {gw.w[j], gw.w[j]};
            f32x2 a = ra[s], b = rb[s];
            f32x2 ga = g2 * a, gb = g2 * b;
            m1 += ga; m2 += gb;
            xx += ga * a; yy += gb * b; zz += ga * b;
        }
        A4[buf][3 + tx] = __builtin_shufflevector(m1, m2, 0, 1, 2, 3);
        B4[buf][3 + tx] = __builtin_shufflevector(xx, yy, 0, 1, 2, 3);
        Z2[buf][3 + tx] = zz;
    };

    // horizontal 11-tap + SSIM for one buffered row
    auto hpass = [&](int buf) {
        f32x2 OM1 = {0.f, 0.f}, OM2 = OM1, OXX = OM1, OYY = OM1, OZZ = OM1;
        {   // jj = 0: only e1 with (g0, 0)
            f32x4 pa = A4[buf][tx], pb = B4[buf][tx];
            f32x2 pz = Z2[buf][tx];
            const f32x2 c = {gw.w[0], 0.f};
            OM1 += c * __builtin_shufflevector(pa, pa, 1, 1);
            OM2 += c * __builtin_shufflevector(pa, pa, 3, 3);
            OXX += c * __builtin_shufflevector(pb, pb, 1, 1);
            OYY += c * __builtin_shufflevector(pb, pb, 3, 3);
            OZZ += c * __builtin_shufflevector(pz, pz, 1, 1);
        }
        #pragma unroll
        for (int jj = 1; jj <= 5; jj++) {
            f32x4 pa = A4[buf][tx + jj], pb = B4[buf][tx + jj];
            f32x2 pz = Z2[buf][tx + jj];
            const f32x2 cA = {gw.w[2 * jj - 1], gw.w[2 * jj - 2]};
            const f32x2 cB = {gw.w[2 * jj],     gw.w[2 * jj - 1]};
            OM1 += cA * __builtin_shufflevector(pa, pa, 0, 0)
                 + cB * __builtin_shufflevector(pa, pa, 1, 1);
            OM2 += cA * __builtin_shufflevector(pa, pa, 2, 2)
                 + cB * __builtin_shufflevector(pa, pa, 3, 3);
            OXX += cA * __builtin_shufflevector(pb, pb, 0, 0)
                 + cB * __builtin_shufflevector(pb, pb, 1, 1);
            OYY += cA * __builtin_shufflevector(pb, pb, 2, 2)
                 + cB * __builtin_shufflevector(pb, pb, 3, 3);
            OZZ += cA * __builtin_shufflevector(pz, pz, 0, 0)
                 + cB * __builtin_shufflevector(pz, pz, 1, 1);
        }
        {   // jj = 6: only e0 with (0, g10)
            f32x4 pa = A4[buf][tx + 6], pb = B4[buf][tx + 6];
            f32x2 pz = Z2[buf][tx + 6];
            const f32x2 c = {0.f, gw.w[10]};
            OM1 += c * __builtin_shufflevector(pa, pa, 0, 0);
            OM2 += c * __builtin_shufflevector(pa, pa, 2, 2);
            OXX += c * __builtin_shufflevector(pb, pb, 0, 0);
            OYY += c * __builtin_shufflevector(pb, pb, 2, 2);
            OZZ += c * __builtin_shufflevector(pz, pz, 0, 0);
        }
        f32x2 m1s = OM1 * OM1, m2s = OM2 * OM2, m12 = OM1 * OM2;
        f32x2 s1 = OXX - m1s, s2 = OYY - m2s, s12 = OZZ - m12;
        f32x2 d1 = m1s + m2s + C1v;
        f32x2 d2 = s1 + s2 + C2v;
        f32x2 num = (2.f * m12 + C1v) * (2.f * s12 + C2v) * (s12 + C2v);
        float d3x = __builtin_amdgcn_sqrtf(s1.x) * __builtin_amdgcn_sqrtf(s2.x) + 9e-4f;
        float d3y = __builtin_amdgcn_sqrtf(s1.y) * __builtin_amdgcn_sqrtf(s2.y) + 9e-4f;
        sum += num.x * __builtin_amdgcn_rcpf(d1.x * d2.x * d3x);
        sum += num.y * __builtin_amdgcn_rcpf(d1.y * d2.y * d3y);
    };

    // main loop: iteration k emits output rows y0+2k, y0+2k+1
    for (int kk = 0; kk < ITER; kk += 6) {
        #pragma unroll
        for (int u = 0; u < 6; u++) {
            const int k = kk + u;
            if (k < ITER) {                       // block-uniform
                // insert this iteration's two rows (t = 10+2k, 11+2k)
                const int s0 = (10 + 2 * u) % 12; // kk%6==0 -> static
                const int s1 = (11 + 2 * u) % 12;
                ra[s0] = aN0; rb[s0] = bN0;
                ra[s1] = aN1; rb[s1] = bN1;

                // prefetch next iteration's two rows (stay in flight across barrier)
                {
                    int r0 = y0 + 7 + 2 * k, r1 = r0 + 1;
                    aN0 = (f32x2){0.f, 0.f}; bN0 = aN0; aN1 = aN0; bN1 = aN0;
                    if (k + 1 < ITER) {
                        if (r0 < IMG) { aN0 = *(const f32x2*)&Ap[(long)r0 * IMG + x0];
                                        bN0 = *(const f32x2*)&Bp[(long)r0 * IMG + x0]; }
                        if (r1 < IMG) { aN1 = *(const f32x2*)&Ap[(long)r1 * IMG + x0];
                                        bN1 = *(const f32x2*)&Bp[(long)r1 * IMG + x0]; }
                    }
                }

                // two vertical sums -> two buffers; one barrier; two h-passes
                const int b0 = (u & 1) * 2;       // even k -> {0,1}, odd -> {2,3}
                vpass(2 * u,     b0);             // row o   uses slots (2k+j)%12
                vpass(2 * u + 1, b0 + 1);         // row o+1 uses slots (2k+1+j)%12
                row_barrier();
                hpass(b0);
                hpass(b0 + 1);
            }
        }
    }

    // block reduction: wave shuffle -> LDS -> one atomic per block
    for (int off = 32; off > 0; off >>= 1)
        sum += __shfl_down(sum, off, 64);
    if ((tx & 63) == 0) bsum[tx >> 6] = sum;
    __syncthreads();
    if (tx == 0) {
        float tot = bsum[0] + bsum[1] + bsum[2] + bsum[3];
        atomicAdd(accp, (double)tot);
    }
}

__global__ void finalize_kernel(const double* __restrict__ acc, float* __restrict__ out)
{
    double loss3 = 1.0 - acc[0] / (64.0 * (double)SLICE);
    double loss2 = 1.0 - acc[1] / (4.0 * (double)SLICE);
    out[0] = (float)(loss3 + loss2);
}

extern "C" void kernel_launch(void* const* d_in, const int* in_sizes, int n_in,
                              void* d_out, int out_size, void* d_ws, size_t ws_size,
                              hipStream_t stream)
{
    const float* img1_3d = (const float*)d_in[0];   // [4,1,16,512,512] -> 64 slices
    const float* img1_2d = (const float*)d_in[1];   // [4,1,512,512]
    const float* img2    = (const float*)d_in[2];   // [4,1,16,512,512]
    float* out = (float*)d_out;

    double* acc = (double*)d_ws;                    // [0]=3D sum, [1]=2D sum
    unsigned int* cnt = (unsigned int*)((char*)d_ws + 16);   // producer counter
    float4* b2 = (float4*)((char*)d_ws + 256);      // 4 MB depth-mean buffer

    // Gaussian weights, like cv2.getGaussianKernel(11, 1.5) in double.
    G11 gw;
    {
        double g[WSZ], s = 0.0;
        for (int i = 0; i < WSZ; i++) {
            double xx = (double)i - (WSZ - 1) / 2.0;
            g[i] = std::exp(-(xx * xx) / (2.0 * 1.5 * 1.5));
            s += g[i];
        }
        for (int i = 0; i < WSZ; i++) gw.w[i] = (float)(g[i] / s);
    }

    // zero acc[0..1] and cnt each launch (graph-replay determinism)
    hipMemsetAsync(d_ws, 0, 32, stream);

    // fused SSIM + depth-mean producer/consumer: 1536 3D bands + 256 2D
    // bands (LAST, gated on the b2 counter) = 1792 blocks.
    ssim_pk_kernel<<<NBLK, 256, 0, stream>>>(img1_3d, img2, img1_2d, b2, acc, cnt, gw);

    finalize_kernel<<<1, 1, 0, stream>>>(acc, out);
}

// Round 21
// 97.108 us; speedup vs baseline: 3.9293x; 3.9293x over previous
//
#include <hip/hip_runtime.h>
#include <cmath>

// SSIM loss, vertical-first row-sliding kernel, two stream-ordered dispatches.
// Round-21 = round-14's champion kernel body byte-for-byte (2 output rows per
// barrier interval, 12-slot f32x2 ring, 4 LDS sets / 42 KB,
// launch_bounds(256,4) -> VGPR 68 no spill) with the work repacked to hide
// the depth-mean AND kill the partial last residency round:
//   3D re-banded to 1280 even bands (64 slices x (16x26 + 4x24 rows)).
//   Dispatch 1 (1792 blocks): 512 3D + 1024 mean-chunk blocks (sandwiched,
//     each writes 256 float4 of b2 = mean16(img2) and exits; they backfill
//     block slots under the running 3D blocks) + 256 3D.
//   Dispatch 2 (768 blocks = EXACTLY one residency round): 512 3D + 256 2D.
// b2 write->read ordering comes from stream ordering between dispatches
// (same mechanism R14 used) - no fences, no spinning (R20's fused
// producer/consumer gate collapsed to 10% VALUBusy; reverted).

#define WSZ 11
#define IMG 512
#define SLICE (IMG * IMG)

typedef float f32x2 __attribute__((ext_vector_type(2)));
typedef float f32x4 __attribute__((ext_vector_type(4)));

struct G11 { float w[WSZ]; };

// LDS-visibility-only barrier: wait own LDS ops, rendezvous; vmem stays in flight.
__device__ __forceinline__ void row_barrier()
{
    asm volatile("s_waitcnt lgkmcnt(0)" ::: "memory");
    __builtin_amdgcn_s_barrier();
}

__global__ __launch_bounds__(256, 4)
void ssim_pk_kernel(const float* __restrict__ A3, const float* __restrict__ B3,
                    const float* __restrict__ A2, float4* __restrict__ b2,
                    double* __restrict__ acc, G11 gw, int disp)
{
    __shared__ f32x4 A4[4][262];   // (m1,m2) pairs, 3-slot pad each side
    __shared__ f32x4 B4[4][262];   // (xx,yy) pairs
    __shared__ f32x2 Z2[4][262];   // zz pairs
    __shared__ float bsum[4];

    const int tx = threadIdx.x;    // 0..255 = column pair index
    const int x0 = tx * 2;
    const int unit = blockIdx.x;

    // ---------------- work decode ----------------
    // 3D bands: 1280 total, 20/slice (16 bands of 26 rows + 4 of 24).
    // disp 0 (1792 blocks): [0,512) = 3D bands 0..511;
    //                       [512,1536) = mean chunks 0..1023 (write b2, exit);
    //                       [1536,1792) = 3D bands 512..767.
    // disp 1 (768 blocks):  [0,512) = 3D bands 768..1279;
    //                       [512,768) = 2D bands (4 imgs x 64 bands of 8 rows).
    const float* Ap;
    const float* Bp;
    double* accp;
    int y0, BAND;
    int b3 = -1;
    if (disp == 0) {
        if (unit >= 512 && unit < 1536) {
            // mean-chunk block: 256 coalesced float4 of b2 = mean16(img2)
            const int per = SLICE / 4;                 // 65536
            int e = (unit - 512) * 256 + tx;           // 0 .. 262143
            int img = e >> 16;                         // / per
            int p   = e & (per - 1);
            const float4* src = (const float4*)B3 + (long)img * 16 * per + p;
            float sx = 0.f, sy = 0.f, sz = 0.f, sw = 0.f;
            #pragma unroll
            for (int d = 0; d < 16; d++) {
                float4 v = src[(long)d * per];
                sx += v.x; sy += v.y; sz += v.z; sw += v.w;
            }
            float4 o;
            o.x = sx * 0.0625f; o.y = sy * 0.0625f;
            o.z = sz * 0.0625f; o.w = sw * 0.0625f;
            b2[e] = o;
            return;
        }
        b3 = (unit < 512) ? unit : (unit - 1024);      // 1536..1791 -> 512..767
    } else {
        if (unit < 512) {
            b3 = 768 + unit;                           // 3D bands 768..1279
        } else {
            int uu = unit - 512;
            int img  = uu >> 6;
            int band = uu & 63;
            Ap = A2 + (long)img * SLICE;
            Bp = (const float*)b2 + (long)img * SLICE;
            accp = acc + 1;
            y0 = band * 8;
            BAND = 8;
        }
    }
    if (b3 >= 0) {
        int slice = b3 / 20;
        int band  = b3 - slice * 20;
        Ap = A3 + (long)slice * SLICE;
        Bp = B3 + (long)slice * SLICE;
        accp = acc + 0;
        if (band < 16) { y0 = band * 26;              BAND = 26; }
        else           { y0 = 416 + (band - 16) * 24; BAND = 24; }
    }
    const int ITER = BAND >> 1;    // 2 output rows per iteration (13, 12, or 4)

    // zero pads: pair slots 0..2 and 259..261, all 4 buffer sets
    if (tx < 3) {
        f32x4 z4 = {0.f, 0.f, 0.f, 0.f};
        f32x2 z2 = {0.f, 0.f};
        #pragma unroll
        for (int b = 0; b < 4; b++) {
            A4[b][tx] = z4; A4[b][259 + tx] = z4;
            B4[b][tx] = z4; B4[b][259 + tx] = z4;
            Z2[b][tx] = z2; Z2[b][259 + tx] = z2;
        }
    }

    // 12-slot register ring of raw (a,b) pairs; slot = t % 12, t = row - (y0-5)
    f32x2 ra[12], rb[12];

    float sum = 0.f;
    const f32x2 C1v = {1e-4f, 1e-4f};
    const f32x2 C2v = {9e-4f, 9e-4f};

    // warmup: insert input rows t = 0..9 (rows y0-5 .. y0+4)
    #pragma unroll
    for (int t = 0; t < 10; t++) {
        int r = y0 - 5 + t;
        f32x2 a = {0.f, 0.f}, b = {0.f, 0.f};
        if (r >= 0) {                       // r < IMG always in warmup
            a = *(const f32x2*)&Ap[(long)r * IMG + x0];
            b = *(const f32x2*)&Bp[(long)r * IMG + x0];
        }
        ra[t] = a; rb[t] = b;
    }
    ra[10] = (f32x2){0.f, 0.f}; rb[10] = (f32x2){0.f, 0.f};
    ra[11] = (f32x2){0.f, 0.f}; rb[11] = (f32x2){0.f, 0.f};

    // prefetch iteration 0's two input rows (t = 10, 11 -> rows y0+5, y0+6)
    f32x2 aN0 = {0.f, 0.f}, bN0 = aN0, aN1 = aN0, bN1 = aN0;
    {
        int r0 = y0 + 5, r1 = y0 + 6;
        if (r0 < IMG) { aN0 = *(const f32x2*)&Ap[(long)r0 * IMG + x0];
                        bN0 = *(const f32x2*)&Bp[(long)r0 * IMG + x0]; }
        if (r1 < IMG) { aN1 = *(const f32x2*)&Ap[(long)r1 * IMG + x0];
                        bN1 = *(const f32x2*)&Bp[(long)r1 * IMG + x0]; }
    }

    // vertical 11-tap for one output row; slots (base+j)%12, weights g[j]
    auto vpass = [&](int base, int buf) {
        f32x2 m1 = {0.f, 0.f}, m2 = m1, xx = m1, yy = m1, zz = m1;
        #pragma unroll
        for (int j = 0; j < 11; j++) {
            const int s = (base + j) % 12;           // compile-time
            const f32x2 g2 = {gw.w[j], gw.w[j]};
            f32x2 a = ra[s], b = rb[s];
            f32x2 ga = g2 * a, gb = g2 * b;
            m1 += ga; m2 += gb;
            xx += ga * a; yy += gb * b; zz += ga * b;
        }
        A4[buf][3 + tx] = __builtin_shufflevector(m1, m2, 0, 1, 2, 3);
        B4[buf][3 + tx] = __builtin_shufflevector(xx, yy, 0, 1, 2, 3);
        Z2[buf][3 + tx] = zz;
    };

    // horizontal 11-tap + SSIM for one buffered row
    auto hpass = [&](int buf) {
        f32x2 OM1 = {0.f, 0.f}, OM2 = OM1, OXX = OM1, OYY = OM1, OZZ = OM1;
        {   // jj = 0: only e1 with (g0, 0)
            f32x4 pa = A4[buf][tx], pb = B4[buf][tx];
            f32x2 pz = Z2[buf][tx];
            const f32x2 c = {gw.w[0], 0.f};
            OM1 += c * __builtin_shufflevector(pa, pa, 1, 1);
            OM2 += c * __builtin_shufflevector(pa, pa, 3, 3);
            OXX += c * __builtin_shufflevector(pb, pb, 1, 1);
            OYY += c * __builtin_shufflevector(pb, pb, 3, 3);
            OZZ += c * __builtin_shufflevector(pz, pz, 1, 1);
        }
        #pragma unroll
        for (int jj = 1; jj <= 5; jj++) {
            f32x4 pa = A4[buf][tx + jj], pb = B4[buf][tx + jj];
            f32x2 pz = Z2[buf][tx + jj];
            const f32x2 cA = {gw.w[2 * jj - 1], gw.w[2 * jj - 2]};
            const f32x2 cB = {gw.w[2 * jj],     gw.w[2 * jj - 1]};
            OM1 += cA * __builtin_shufflevector(pa, pa, 0, 0)
                 + cB * __builtin_shufflevector(pa, pa, 1, 1);
            OM2 += cA * __builtin_shufflevector(pa, pa, 2, 2)
                 + cB * __builtin_shufflevector(pa, pa, 3, 3);
            OXX += cA * __builtin_shufflevector(pb, pb, 0, 0)
                 + cB * __builtin_shufflevector(pb, pb, 1, 1);
            OYY += cA * __builtin_shufflevector(pb, pb, 2, 2)
                 + cB * __builtin_shufflevector(pb, pb, 3, 3);
            OZZ += cA * __builtin_shufflevector(pz, pz, 0, 0)
                 + cB * __builtin_shufflevector(pz, pz, 1, 1);
        }
        {   // jj = 6: only e0 with (0, g10)
            f32x4 pa = A4[buf][tx + 6], pb = B4[buf][tx + 6];
            f32x2 pz = Z2[buf][tx + 6];
            const f32x2 c = {0.f, gw.w[10]};
            OM1 += c * __builtin_shufflevector(pa, pa, 0, 0);
            OM2 += c * __builtin_shufflevector(pa, pa, 2, 2);
            OXX += c * __builtin_shufflevector(pb, pb, 0, 0);
            OYY += c * __builtin_shufflevector(pb, pb, 2, 2);
            OZZ += c * __builtin_shufflevector(pz, pz, 0, 0);
        }
        f32x2 m1s = OM1 * OM1, m2s = OM2 * OM2, m12 = OM1 * OM2;
        f32x2 s1 = OXX - m1s, s2 = OYY - m2s, s12 = OZZ - m12;
        f32x2 d1 = m1s + m2s + C1v;
        f32x2 d2 = s1 + s2 + C2v;
        f32x2 num = (2.f * m12 + C1v) * (2.f * s12 + C2v) * (s12 + C2v);
        float d3x = __builtin_amdgcn_sqrtf(s1.x) * __builtin_amdgcn_sqrtf(s2.x) + 9e-4f;
        float d3y = __builtin_amdgcn_sqrtf(s1.y) * __builtin_amdgcn_sqrtf(s2.y) + 9e-4f;
        sum += num.x * __builtin_amdgcn_rcpf(d1.x * d2.x * d3x);
        sum += num.y * __builtin_amdgcn_rcpf(d1.y * d2.y * d3y);
    };

    // main loop: iteration k emits output rows y0+2k, y0+2k+1
    for (int kk = 0; kk < ITER; kk += 6) {
        #pragma unroll
        for (int u = 0; u < 6; u++) {
            const int k = kk + u;
            if (k < ITER) {                       // block-uniform
                // insert this iteration's two rows (t = 10+2k, 11+2k)
                const int s0 = (10 + 2 * u) % 12; // kk%6==0 -> static
                const int s1 = (11 + 2 * u) % 12;
                ra[s0] = aN0; rb[s0] = bN0;
                ra[s1] = aN1; rb[s1] = bN1;

                // prefetch next iteration's two rows (stay in flight across barrier)
                {
                    int r0 = y0 + 7 + 2 * k, r1 = r0 + 1;
                    aN0 = (f32x2){0.f, 0.f}; bN0 = aN0; aN1 = aN0; bN1 = aN0;
                    if (k + 1 < ITER) {
                        if (r0 < IMG) { aN0 = *(const f32x2*)&Ap[(long)r0 * IMG + x0];
                                        bN0 = *(const f32x2*)&Bp[(long)r0 * IMG + x0]; }
                        if (r1 < IMG) { aN1 = *(const f32x2*)&Ap[(long)r1 * IMG + x0];
                                        bN1 = *(const f32x2*)&Bp[(long)r1 * IMG + x0]; }
                    }
                }

                // two vertical sums -> two buffers; one barrier; two h-passes
                const int b0 = (u & 1) * 2;       // even k -> {0,1}, odd -> {2,3}
                vpass(2 * u,     b0);             // row o   uses slots (2k+j)%12
                vpass(2 * u + 1, b0 + 1);         // row o+1 uses slots (2k+1+j)%12
                row_barrier();
                hpass(b0);
                hpass(b0 + 1);
            }
        }
    }

    // block reduction: wave shuffle -> LDS -> one atomic per block
    for (int off = 32; off > 0; off >>= 1)
        sum += __shfl_down(sum, off, 64);
    if ((tx & 63) == 0) bsum[tx >> 6] = sum;
    __syncthreads();
    if (tx == 0) {
        float tot = bsum[0] + bsum[1] + bsum[2] + bsum[3];
        atomicAdd(accp, (double)tot);
    }
}

__global__ void finalize_kernel(const double* __restrict__ acc, float* __restrict__ out)
{
    double loss3 = 1.0 - acc[0] / (64.0 * (double)SLICE);
    double loss2 = 1.0 - acc[1] / (4.0 * (double)SLICE);
    out[0] = (float)(loss3 + loss2);
}

extern "C" void kernel_launch(void* const* d_in, const int* in_sizes, int n_in,
                              void* d_out, int out_size, void* d_ws, size_t ws_size,
                              hipStream_t stream)
{
    const float* img1_3d = (const float*)d_in[0];   // [4,1,16,512,512] -> 64 slices
    const float* img1_2d = (const float*)d_in[1];   // [4,1,512,512]
    const float* img2    = (const float*)d_in[2];   // [4,1,16,512,512]
    float* out = (float*)d_out;

    double* acc = (double*)d_ws;                    // [0]=3D sum, [1]=2D sum
    float4* b2  = (float4*)((char*)d_ws + 256);     // 4 MB depth-mean buffer

    // Gaussian weights, like cv2.getGaussianKernel(11, 1.5) in double.
    G11 gw;
    {
        double g[WSZ], s = 0.0;
        for (int i = 0; i < WSZ; i++) {
            double xx = (double)i - (WSZ - 1) / 2.0;
            g[i] = std::exp(-(xx * xx) / (2.0 * 1.5 * 1.5));
            s += g[i];
        }
        for (int i = 0; i < WSZ; i++) gw.w[i] = (float)(g[i] / s);
    }

    hipMemsetAsync(acc, 0, 2 * sizeof(double), stream);

    // dispatch 1: 512 3D bands + 1024 mean-chunk blocks (sandwiched) + 256 3D
    ssim_pk_kernel<<<1792, 256, 0, stream>>>(img1_3d, img2, img1_2d, b2, acc, gw, 0);

    // dispatch 2 (one full residency round): 512 3D bands + 256 2D bands.
    // b2 ready via stream ordering.
    ssim_pk_kernel<<<768, 256, 0, stream>>>(img1_3d, img2, img1_2d, b2, acc, gw, 1);

    finalize_kernel<<<1, 1, 0, stream>>>(acc, out);
}

// Round 22
// 93.958 us; speedup vs baseline: 4.0610x; 1.0335x over previous
//
#include <hip/hip_runtime.h>
#include <cmath>

// SSIM loss, vertical-first row-sliding kernel, merged 3D+2D dispatch.
// FINAL (= round-14 champion, 94.0 us measured): two output rows per barrier
// interval: 12-slot register ring, insert 2 input rows/iter, 2 vertical sums
// -> 2 of 4 LDS buffer sets (alternating {0,1}/{2,3}), ONE lgkmcnt-only
// barrier, then two INDEPENDENT horizontal+SSIM passes (2x MLP in the
// stall-dominated read section). launch_bounds(256,4) -> VGPR 68, no spill.
// Session ledger: row-sliding structure 894->186; merged grid + packed f32x2
// math ->120; ILP-2-per-barrier ->94. Neutral/regressed: occupancy plays
// (residency measured-pinned ~3 blocks/CU regardless of LDS/grid), barrier
// removal, vmcnt-light barriers alone, ILP-4 (spill), horizontal-first
// (spill), grid repacks, in-kernel producer/consumer fusion (catastrophic),
// dispatch splitting. Per-interval latency is the binding constraint.

#define WSZ 11
#define IMG 512
#define SLICE (IMG * IMG)

typedef float f32x2 __attribute__((ext_vector_type(2)));
typedef float f32x4 __attribute__((ext_vector_type(4)));

struct G11 { float w[WSZ]; };

// LDS-visibility-only barrier: wait own LDS ops, rendezvous; vmem stays in flight.
__device__ __forceinline__ void row_barrier()
{
    asm volatile("s_waitcnt lgkmcnt(0)" ::: "memory");
    __builtin_amdgcn_s_barrier();
}

__global__ __launch_bounds__(256, 4)
void ssim_pk_kernel(const float* __restrict__ A3, const float* __restrict__ B3,
                    const float* __restrict__ A2, const float* __restrict__ B2,
                    double* __restrict__ acc, G11 gw)
{
    __shared__ f32x4 A4[4][262];   // (m1,m2) pairs, 3-slot pad each side
    __shared__ f32x4 B4[4][262];   // (xx,yy) pairs
    __shared__ f32x2 Z2[4][262];   // zz pairs
    __shared__ float bsum[4];

    const int tx = threadIdx.x;    // 0..255 = column pair index
    const int x0 = tx * 2;

    // decode work unit: [0,1536) = 3D slice-bands (24/slice: 16x22 + 8x20 rows),
    // [1536,1792) = 2D bands (4 imgs x 64 bands of 8 rows, B2 = depth mean)
    const int unit = blockIdx.x;
    const float* Ap;
    const float* Bp;
    double* accp;
    int y0, BAND;
    if (unit < 1536) {
        int slice = unit / 24;
        int band  = unit - slice * 24;
        Ap = A3 + (long)slice * SLICE;
        Bp = B3 + (long)slice * SLICE;
        accp = acc + 0;
        if (band < 16) { y0 = band * 22;              BAND = 22; }
        else           { y0 = 352 + (band - 16) * 20; BAND = 20; }
    } else {
        int uu = unit - 1536;
        int img  = uu >> 6;
        int band = uu & 63;
        Ap = A2 + (long)img * SLICE;
        Bp = B2 + (long)img * SLICE;
        accp = acc + 1;
        y0 = band * 8;
        BAND = 8;
    }
    const int ITER = BAND >> 1;    // 2 output rows per iteration

    // zero pads: pair slots 0..2 and 259..261, all 4 buffer sets
    if (tx < 3) {
        f32x4 z4 = {0.f, 0.f, 0.f, 0.f};
        f32x2 z2 = {0.f, 0.f};
        #pragma unroll
        for (int b = 0; b < 4; b++) {
            A4[b][tx] = z4; A4[b][259 + tx] = z4;
            B4[b][tx] = z4; B4[b][259 + tx] = z4;
            Z2[b][tx] = z2; Z2[b][259 + tx] = z2;
        }
    }

    // 12-slot register ring of raw (a,b) pairs; slot = t % 12, t = row - (y0-5)
    f32x2 ra[12], rb[12];

    float sum = 0.f;
    const f32x2 C1v = {1e-4f, 1e-4f};
    const f32x2 C2v = {9e-4f, 9e-4f};

    // warmup: insert input rows t = 0..9 (rows y0-5 .. y0+4)
    #pragma unroll
    for (int t = 0; t < 10; t++) {
        int r = y0 - 5 + t;
        f32x2 a = {0.f, 0.f}, b = {0.f, 0.f};
        if (r >= 0) {                       // r < IMG always in warmup
            a = *(const f32x2*)&Ap[(long)r * IMG + x0];
            b = *(const f32x2*)&Bp[(long)r * IMG + x0];
        }
        ra[t] = a; rb[t] = b;
    }
    ra[10] = (f32x2){0.f, 0.f}; rb[10] = (f32x2){0.f, 0.f};
    ra[11] = (f32x2){0.f, 0.f}; rb[11] = (f32x2){0.f, 0.f};

    // prefetch iteration 0's two input rows (t = 10, 11 -> rows y0+5, y0+6)
    f32x2 aN0 = {0.f, 0.f}, bN0 = aN0, aN1 = aN0, bN1 = aN0;
    {
        int r0 = y0 + 5, r1 = y0 + 6;
        if (r0 < IMG) { aN0 = *(const f32x2*)&Ap[(long)r0 * IMG + x0];
                        bN0 = *(const f32x2*)&Bp[(long)r0 * IMG + x0]; }
        if (r1 < IMG) { aN1 = *(const f32x2*)&Ap[(long)r1 * IMG + x0];
                        bN1 = *(const f32x2*)&Bp[(long)r1 * IMG + x0]; }
    }

    // vertical 11-tap for one output row; slots (base+j)%12, weights g[j]
    auto vpass = [&](int base, int buf) {
        f32x2 m1 = {0.f, 0.f}, m2 = m1, xx = m1, yy = m1, zz = m1;
        #pragma unroll
        for (int j = 0; j < 11; j++) {
            const int s = (base + j) % 12;           // compile-time
            const f32x2 g2 = {gw.w[j], gw.w[j]};
            f32x2 a = ra[s], b = rb[s];
            f32x2 ga = g2 * a, gb = g2 * b;
            m1 += ga; m2 += gb;
            xx += ga * a; yy += gb * b; zz += ga * b;
        }
        A4[buf][3 + tx] = __builtin_shufflevector(m1, m2, 0, 1, 2, 3);
        B4[buf][3 + tx] = __builtin_shufflevector(xx, yy, 0, 1, 2, 3);
        Z2[buf][3 + tx] = zz;
    };

    // horizontal 11-tap + SSIM for one buffered row
    auto hpass = [&](int buf) {
        f32x2 OM1 = {0.f, 0.f}, OM2 = OM1, OXX = OM1, OYY = OM1, OZZ = OM1;
        {   // jj = 0: only e1 with (g0, 0)
            f32x4 pa = A4[buf][tx], pb = B4[buf][tx];
            f32x2 pz = Z2[buf][tx];
            const f32x2 c = {gw.w[0], 0.f};
            OM1 += c * __builtin_shufflevector(pa, pa, 1, 1);
            OM2 += c * __builtin_shufflevector(pa, pa, 3, 3);
            OXX += c * __builtin_shufflevector(pb, pb, 1, 1);
            OYY += c * __builtin_shufflevector(pb, pb, 3, 3);
            OZZ += c * __builtin_shufflevector(pz, pz, 1, 1);
        }
        #pragma unroll
        for (int jj = 1; jj <= 5; jj++) {
            f32x4 pa = A4[buf][tx + jj], pb = B4[buf][tx + jj];
            f32x2 pz = Z2[buf][tx + jj];
            const f32x2 cA = {gw.w[2 * jj - 1], gw.w[2 * jj - 2]};
            const f32x2 cB = {gw.w[2 * jj],     gw.w[2 * jj - 1]};
            OM1 += cA * __builtin_shufflevector(pa, pa, 0, 0)
                 + cB * __builtin_shufflevector(pa, pa, 1, 1);
            OM2 += cA * __builtin_shufflevector(pa, pa, 2, 2)
                 + cB * __builtin_shufflevector(pa, pa, 3, 3);
            OXX += cA * __builtin_shufflevector(pb, pb, 0, 0)
                 + cB * __builtin_shufflevector(pb, pb, 1, 1);
            OYY += cA * __builtin_shufflevector(pb, pb, 2, 2)
                 + cB * __builtin_shufflevector(pb, pb, 3, 3);
            OZZ += cA * __builtin_shufflevector(pz, pz, 0, 0)
                 + cB * __builtin_shufflevector(pz, pz, 1, 1);
        }
        {   // jj = 6: only e0 with (0, g10)
            f32x4 pa = A4[buf][tx + 6], pb = B4[buf][tx + 6];
            f32x2 pz = Z2[buf][tx + 6];
            const f32x2 c = {0.f, gw.w[10]};
            OM1 += c * __builtin_shufflevector(pa, pa, 0, 0);
            OM2 += c * __builtin_shufflevector(pa, pa, 2, 2);
            OXX += c * __builtin_shufflevector(pb, pb, 0, 0);
            OYY += c * __builtin_shufflevector(pb, pb, 2, 2);
            OZZ += c * __builtin_shufflevector(pz, pz, 0, 0);
        }
        f32x2 m1s = OM1 * OM1, m2s = OM2 * OM2, m12 = OM1 * OM2;
        f32x2 s1 = OXX - m1s, s2 = OYY - m2s, s12 = OZZ - m12;
        f32x2 d1 = m1s + m2s + C1v;
        f32x2 d2 = s1 + s2 + C2v;
        f32x2 num = (2.f * m12 + C1v) * (2.f * s12 + C2v) * (s12 + C2v);
        float d3x = __builtin_amdgcn_sqrtf(s1.x) * __builtin_amdgcn_sqrtf(s2.x) + 9e-4f;
        float d3y = __builtin_amdgcn_sqrtf(s1.y) * __builtin_amdgcn_sqrtf(s2.y) + 9e-4f;
        sum += num.x * __builtin_amdgcn_rcpf(d1.x * d2.x * d3x);
        sum += num.y * __builtin_amdgcn_rcpf(d1.y * d2.y * d3y);
    };

    // main loop: iteration k emits output rows y0+2k, y0+2k+1
    for (int kk = 0; kk < ITER; kk += 6) {
        #pragma unroll
        for (int u = 0; u < 6; u++) {
            const int k = kk + u;
            if (k < ITER) {                       // block-uniform
                // insert this iteration's two rows (t = 10+2k, 11+2k)
                const int s0 = (10 + 2 * u) % 12; // kk%6==0 -> static
                const int s1 = (11 + 2 * u) % 12;
                ra[s0] = aN0; rb[s0] = bN0;
                ra[s1] = aN1; rb[s1] = bN1;

                // prefetch next iteration's two rows (stay in flight across barrier)
                {
                    int r0 = y0 + 7 + 2 * k, r1 = r0 + 1;
                    aN0 = (f32x2){0.f, 0.f}; bN0 = aN0; aN1 = aN0; bN1 = aN0;
                    if (k + 1 < ITER) {
                        if (r0 < IMG) { aN0 = *(const f32x2*)&Ap[(long)r0 * IMG + x0];
                                        bN0 = *(const f32x2*)&Bp[(long)r0 * IMG + x0]; }
                        if (r1 < IMG) { aN1 = *(const f32x2*)&Ap[(long)r1 * IMG + x0];
                                        bN1 = *(const f32x2*)&Bp[(long)r1 * IMG + x0]; }
                    }
                }

                // two vertical sums -> two buffers; one barrier; two h-passes
                const int b0 = (u & 1) * 2;       // even k -> {0,1}, odd -> {2,3}
                vpass(2 * u,     b0);             // row o   uses slots (2k+j)%12
                vpass(2 * u + 1, b0 + 1);         // row o+1 uses slots (2k+1+j)%12
                row_barrier();
                hpass(b0);
                hpass(b0 + 1);
            }
        }
    }

    // block reduction: wave shuffle -> LDS -> one atomic per block
    for (int off = 32; off > 0; off >>= 1)
        sum += __shfl_down(sum, off, 64);
    if ((tx & 63) == 0) bsum[tx >> 6] = sum;
    __syncthreads();
    if (tx == 0) {
        float tot = bsum[0] + bsum[1] + bsum[2] + bsum[3];
        atomicAdd(accp, (double)tot);
    }
}

// b2 = mean over 16 depth slices of img2, vectorized float4 (BW-bound).
__global__ __launch_bounds__(256) void depth_mean4_kernel(
    const float4* __restrict__ img2, float4* __restrict__ b2)
{
    const int per = SLICE / 4;                       // 65536 float4 per slice
    int idx = blockIdx.x * 256 + threadIdx.x;        // 0 .. 4*per-1
    int b = idx >> 16;
    int p = idx & (per - 1);
    const float4* src = img2 + (long)b * 16 * per + p;
    float sx = 0.f, sy = 0.f, sz = 0.f, sw = 0.f;
    #pragma unroll
    for (int d = 0; d < 16; d++) {
        float4 v = src[(long)d * per];
        sx += v.x; sy += v.y; sz += v.z; sw += v.w;
    }
    float4 o; o.x = sx * 0.0625f; o.y = sy * 0.0625f; o.z = sz * 0.0625f; o.w = sw * 0.0625f;
    b2[idx] = o;
}

__global__ void finalize_kernel(const double* __restrict__ acc, float* __restrict__ out)
{
    double loss3 = 1.0 - acc[0] / (64.0 * (double)SLICE);
    double loss2 = 1.0 - acc[1] / (4.0 * (double)SLICE);
    out[0] = (float)(loss3 + loss2);
}

extern "C" void kernel_launch(void* const* d_in, const int* in_sizes, int n_in,
                              void* d_out, int out_size, void* d_ws, size_t ws_size,
                              hipStream_t stream)
{
    const float* img1_3d = (const float*)d_in[0];   // [4,1,16,512,512] -> 64 slices
    const float* img1_2d = (const float*)d_in[1];   // [4,1,512,512]
    const float* img2    = (const float*)d_in[2];   // [4,1,16,512,512]
    float* out = (float*)d_out;

    double* acc = (double*)d_ws;                    // [0]=3D sum, [1]=2D sum
    float*  b2  = (float*)((char*)d_ws + 256);      // 4 MB depth-mean buffer

    // Gaussian weights, like cv2.getGaussianKernel(11, 1.5) in double.
    G11 gw;
    {
        double g[WSZ], s = 0.0;
        for (int i = 0; i < WSZ; i++) {
            double xx = (double)i - (WSZ - 1) / 2.0;
            g[i] = std::exp(-(xx * xx) / (2.0 * 1.5 * 1.5));
            s += g[i];
        }
        for (int i = 0; i < WSZ; i++) gw.w[i] = (float)(g[i] / s);
    }

    hipMemsetAsync(acc, 0, 2 * sizeof(double), stream);

    // depth mean of img2 -> b2 (68 MB, ~12 us)
    depth_mean4_kernel<<<(4 * SLICE / 4) / 256, 256, 0, stream>>>(
        (const float4*)img2, (float4*)b2);

    // merged SSIM: 1536 3D bands (64 slices x (16x22 + 8x20 rows))
    // + 256 2D bands (4 imgs x 64 bands of 8 rows) = 1792 blocks.
    ssim_pk_kernel<<<1792, 256, 0, stream>>>(img1_3d, img2, img1_2d, b2, acc, gw);

    finalize_kernel<<<1, 1, 0, stream>>>(acc, out);
}